// Round 5
// baseline (272.576 us; speedup 1.0000x reference)
//
#include <hip/hip_runtime.h>
#include <hip/hip_bf16.h>

typedef __attribute__((ext_vector_type(8))) short short8;
typedef __attribute__((ext_vector_type(4))) float floatx4;

#define NN 4096

static __device__ __forceinline__ unsigned f2bf_rne(float x) {
    union { float f; unsigned u; } v; v.f = x;
    unsigned r = v.u + 0x7fffu + ((v.u >> 16) & 1u);
    return r >> 16;
}
static __device__ __forceinline__ float bf2f(unsigned hi) {
    union { unsigned u; float f; } v; v.u = hi << 16; return v.f;
}

// ---- wc: Wfb[n*64+k] = bf16(W1@W2)[k][n]; w1a = {W1@aL, W1@aR}; zero num+den.
__global__ void wc_kernel(const float* __restrict__ W1,
                          const float* __restrict__ W2,
                          const float* __restrict__ alpha,
                          unsigned short* __restrict__ Wfb,
                          float* __restrict__ w1a,
                          float* __restrict__ numden) {   // num(4MiB)+den(64KiB) contiguous
    __shared__ float red[4][64];
    const int k = blockIdx.x;
    const int t = threadIdx.x;
    const int c = t & 63, mq = t >> 6;

    // zero num+den: 1064960 floats = 266240 float4s over 64x256 threads
    float4 z = {0.f, 0.f, 0.f, 0.f};
    for (int idx = blockIdx.x * 256 + t; idx < 266240; idx += 64 * 256)
        ((float4*)numden)[idx] = z;

    float p = 0.f;
    #pragma unroll
    for (int mm = 0; mm < 16; ++mm) {
        int mrow = mq * 16 + mm;
        p += W1[k * 64 + mrow] * W2[mrow * 64 + c];
    }
    red[mq][c] = p;
    __syncthreads();
    if (t < 64) {
        float wcv = (red[0][t] + red[1][t]) + (red[2][t] + red[3][t]);
        Wfb[t * 64 + k] = (unsigned short)f2bf_rne(wcv);   // [n=t][k]
        float v = W1[k * 64 + t];
        float pl = v * alpha[t], pr = v * alpha[64 + t];
        #pragma unroll
        for (int off = 32; off > 0; off >>= 1) {
            pl += __shfl_xor(pl, off, 64);
            pr += __shfl_xor(pr, off, 64);
        }
        if (t == 0) { w1a[k] = pl; w1a[64 + k] = pr; }
    }
}

// ---- prep (all-MFMA): G = X@Wc -> Gt bf16 [b*64+c][4096]; lv/rv fp32 exact path.
__global__ __launch_bounds__(256, 4)
void prep_kernel(const float* __restrict__ X,
                 const unsigned short* __restrict__ Wfb,
                 const float* __restrict__ w1a,
                 unsigned short* __restrict__ Gt,
                 float* __restrict__ lv,
                 float* __restrict__ rv) {
    __shared__ float w1s[128];
    __shared__ float Gs[64][68];
    const int t = threadIdx.x;
    const int row0 = blockIdx.x * 64;            // flat b*N + n
    const int b = row0 >> 12, n0 = row0 & (NN - 1);
    const int w = t >> 6, lane = t & 63;
    const int m = lane & 15, q = lane >> 4;
    if (t < 128) w1s[t] = w1a[t];

    const int row = row0 + w * 16 + m;
    const float* xp = X + (size_t)row * 64;
    float4 x0 = *(const float4*)(xp + q * 8);
    float4 x1 = *(const float4*)(xp + q * 8 + 4);
    float4 x2 = *(const float4*)(xp + 32 + q * 8);
    float4 x3 = *(const float4*)(xp + 32 + q * 8 + 4);
    const float xs[16] = {x0.x,x0.y,x0.z,x0.w, x1.x,x1.y,x1.z,x1.w,
                          x2.x,x2.y,x2.z,x2.w, x3.x,x3.y,x3.z,x3.w};
    __syncthreads();

    float pl = 0.f, pr = 0.f;
    #pragma unroll
    for (int ks = 0; ks < 2; ++ks)
        #pragma unroll
        for (int j = 0; j < 8; ++j) {
            int k = ks * 32 + q * 8 + j;
            float xv = xs[ks * 8 + j];
            pl += xv * w1s[k];
            pr += xv * w1s[64 + k];
        }
    pl += __shfl_xor(pl, 16, 64); pl += __shfl_xor(pl, 32, 64);
    pr += __shfl_xor(pr, 16, 64); pr += __shfl_xor(pr, 32, 64);
    if (q == 0) { lv[row] = pl; rv[row] = pr; }

    short8 ah[2], al[2];
    #pragma unroll
    for (int ks = 0; ks < 2; ++ks)
        #pragma unroll
        for (int j = 0; j < 8; ++j) {
            float f = xs[ks * 8 + j];
            unsigned hb = f2bf_rne(f);
            float res = f - bf2f(hb);
            ah[ks][j] = (short)hb;
            al[ks][j] = (short)f2bf_rne(res);
        }

    floatx4 acc[4] = {{0,0,0,0},{0,0,0,0},{0,0,0,0},{0,0,0,0}};
    #pragma unroll
    for (int ks = 0; ks < 2; ++ks)
        #pragma unroll
        for (int nt = 0; nt < 4; ++nt) {
            short8 bf = *(const short8*)(Wfb + (nt * 16 + m) * 64 + ks * 32 + q * 8);
            acc[nt] = __builtin_amdgcn_mfma_f32_16x16x32_bf16(ah[ks], bf, acc[nt], 0, 0, 0);
            acc[nt] = __builtin_amdgcn_mfma_f32_16x16x32_bf16(al[ks], bf, acc[nt], 0, 0, 0);
        }

    #pragma unroll
    for (int nt = 0; nt < 4; ++nt)
        #pragma unroll
        for (int rg = 0; rg < 4; ++rg)
            Gs[nt * 16 + m][w * 16 + q * 4 + rg] = acc[nt][rg];
    __syncthreads();
    unsigned* Gu = (unsigned*)Gt;
    #pragma unroll
    for (int it2 = 0; it2 < 8; ++it2) {
        int c2 = (t >> 5) + it2 * 8;
        int np = t & 31;
        unsigned lo = f2bf_rne(Gs[c2][2 * np]);
        unsigned hi = f2bf_rne(Gs[c2][2 * np + 1]);
        Gu[(((((size_t)(b * 64 + c2)) << 12) + n0) >> 1) + np] = lo | (hi << 16);
    }
}

// ---- attn: producer-computes-E, double-buffered tiles (ONE barrier/iter),
// prefetch depth 2, den via ones-MFMA, j-split 8 (grid 2048 -> 8 blocks/CU).
__global__ __launch_bounds__(256, 6)
void attn_kernel(const float* __restrict__ A,
                 const unsigned short* __restrict__ Gt,
                 const float* __restrict__ lv,
                 const float* __restrict__ rv,
                 float* __restrict__ num,
                 float* __restrict__ den) {
    __shared__ float rs[512];
    __shared__ float lis[64];
    __shared__ __align__(16) unsigned short Es[2][64 * 40];  // stride 40: bank-safe
    __shared__ __align__(16) unsigned short Gs[2][64 * 40];
    const int bx = blockIdx.x;
    const int i0 = (bx & 63) * 64;
    const int b  = (bx >> 6) & 3;
    const int js = bx >> 8;
    const int jbase = js * 512;
    const int t = threadIdx.x;
    const int w = t >> 6, lane = t & 63;
    const int m = lane & 15, q = lane >> 4;
    const int irow = t >> 2, jseg = t & 3;
    const bool hasdiag = ((i0 >> 9) == js);     // diag i in this j-chunk?

    *(float2*)&rs[t * 2] = *(const float2*)(rv + b * NN + jbase + t * 2);
    if (t < 64) lis[t] = lv[b * NN + i0 + t] * 1.44269504f;  // fold log2e

    const float* aRow = A + (size_t)(i0 + irow) * NN + jbase + jseg * 8;
    const unsigned short* gRow = Gt + (((size_t)(b * 64 + irow)) << 12) + jbase + jseg * 8;
    const int ii = i0 + irow;
    __syncthreads();
    const float li = lis[irow];

    floatx4 acc0 = {0,0,0,0}, acc1 = {0,0,0,0}, acc2 = {0,0,0,0},
            acc3 = {0,0,0,0}, accd = {0,0,0,0};
    short8 ones;
    #pragma unroll
    for (int e = 0; e < 8; ++e) ones[e] = (short)0x3F80;    // bf16 1.0

    float4 Pa0[2], Pa1[2]; uint4 Pg[2];
    Pa0[0] = *(const float4*)(aRow);
    Pa1[0] = *(const float4*)(aRow + 4);
    Pg[0]  = *(const uint4*)(gRow);
    Pa0[1] = *(const float4*)(aRow + 32);
    Pa1[1] = *(const float4*)(aRow + 36);
    Pg[1]  = *(const uint4*)(gRow + 32);

    for (int jj = 0; jj < 512; jj += 32) {
        const int s = (jj >> 5) & 1;
        float4 a0 = Pa0[s], a1 = Pa1[s];
        uint4 g = Pg[s];
        const int jn = (jj + 64 < 512) ? jj + 64 : jj;       // clamp tail (re-read, unused)
        Pa0[s] = *(const float4*)(aRow + jn);
        Pa1[s] = *(const float4*)(aRow + jn + 4);
        Pg[s]  = *(const uint4*)(gRow + jn);

        float aa[8] = {a0.x, a0.y, a0.z, a0.w, a1.x, a1.y, a1.z, a1.w};
        if (hasdiag) {                                       // block-uniform branch
            const int jglob = jbase + jj + jseg * 8;
            #pragma unroll
            for (int e = 0; e < 8; ++e)
                if (jglob + e == ii) aa[e] = 1.0f;
        }
        const float* rp = &rs[jj + jseg * 8];
        uint4 epk;
        unsigned ew[4];
        #pragma unroll
        for (int e2 = 0; e2 < 4; ++e2) {
            float sl = li * rp[2 * e2];
            float sh = li * rp[2 * e2 + 1];
            sl = fmaxf(sl, 0.01f * sl);                      // leaky_relu
            sh = fmaxf(sh, 0.01f * sh);
            float el = exp2f(sl) * aa[2 * e2];
            float eh = exp2f(sh) * aa[2 * e2 + 1];
            unsigned ul = __float_as_uint(el) + 0x8000u;     // round-half-up bf16
            unsigned uh = __float_as_uint(eh) + 0x8000u;
            ew[e2] = __builtin_amdgcn_perm(uh, ul, 0x07060302u);
        }
        epk.x = ew[0]; epk.y = ew[1]; epk.z = ew[2]; epk.w = ew[3];

        *(uint4*)&Es[s][irow * 40 + jseg * 8] = epk;
        *(uint4*)&Gs[s][irow * 40 + jseg * 8] = g;
        __syncthreads();                                     // single barrier/iter

        short8 afr = *(const short8*)&Es[s][(w * 16 + m) * 40 + q * 8];
        short8 b0  = *(const short8*)&Gs[s][(m)      * 40 + q * 8];
        short8 b1  = *(const short8*)&Gs[s][(16 + m) * 40 + q * 8];
        short8 b2  = *(const short8*)&Gs[s][(32 + m) * 40 + q * 8];
        short8 b3  = *(const short8*)&Gs[s][(48 + m) * 40 + q * 8];
        acc0 = __builtin_amdgcn_mfma_f32_16x16x32_bf16(afr, b0, acc0, 0, 0, 0);
        acc1 = __builtin_amdgcn_mfma_f32_16x16x32_bf16(afr, b1, acc1, 0, 0, 0);
        acc2 = __builtin_amdgcn_mfma_f32_16x16x32_bf16(afr, b2, acc2, 0, 0, 0);
        acc3 = __builtin_amdgcn_mfma_f32_16x16x32_bf16(afr, b3, acc3, 0, 0, 0);
        accd = __builtin_amdgcn_mfma_f32_16x16x32_bf16(afr, ones, accd, 0, 0, 0);
    }

    // den from ones-MFMA: lane(m==0,q) holds rows q*4+rg of this wave's i-tile
    if (m == 0) {
        #pragma unroll
        for (int rg = 0; rg < 4; ++rg)
            atomicAdd(&den[b * NN + i0 + w * 16 + q * 4 + rg], accd[rg]);
    }

    // C/D layout: col = lane&15, row = q*4 + reg (m89-verified)
    #pragma unroll
    for (int nt = 0; nt < 4; ++nt) {
        floatx4 acc = nt == 0 ? acc0 : nt == 1 ? acc1 : nt == 2 ? acc2 : acc3;
        #pragma unroll
        for (int rg = 0; rg < 4; ++rg) {
            int ir = i0 + w * 16 + q * 4 + rg;
            int cc = nt * 16 + m;
            atomicAdd(&num[((size_t)(b * NN + ir) << 6) + cc], acc[rg]);
        }
    }
}

// ---- out: out = num / den
__global__ void out_kernel(const float* __restrict__ num,
                           const float* __restrict__ den,
                           float* __restrict__ out) {
    int i4 = blockIdx.x * 256 + threadIdx.x;
    float4 v = ((const float4*)num)[i4];
    float r = 1.0f / den[i4 >> 4];
    float4 o; o.x = v.x * r; o.y = v.y * r; o.z = v.z * r; o.w = v.w * r;
    ((float4*)out)[i4] = o;
}

extern "C" void kernel_launch(void* const* d_in, const int* in_sizes, int n_in,
                              void* d_out, int out_size, void* d_ws, size_t ws_size,
                              hipStream_t stream) {
    const float* X     = (const float*)d_in[0];
    const float* A     = (const float*)d_in[1];
    const float* W1    = (const float*)d_in[2];
    const float* W2    = (const float*)d_in[3];
    const float* alpha = (const float*)d_in[4];
    float* out = (float*)d_out;

    char* ws = (char*)d_ws;
    unsigned short* Gt  = (unsigned short*)(ws);           // 2 MiB
    float* lvp = (float*)(ws + 2097152);                   // 64 KiB
    float* rvp = (float*)(ws + 2097152 + 65536);           // 64 KiB
    float* num = (float*)(ws + 2228224);                   // 4 MiB
    float* den = (float*)(ws + 6422528);                   // 64 KiB (contiguous after num)
    unsigned short* Wfb = (unsigned short*)(ws + 6488064); // 8 KiB
    float* w1a = (float*)(ws + 6496256);                   // 512 B

    wc_kernel<<<64, 256, 0, stream>>>(W1, W2, alpha, Wfb, w1a, num);  // also zeroes num+den
    prep_kernel<<<256, 256, 0, stream>>>(X, Wfb, w1a, Gt, lvp, rvp);
    attn_kernel<<<2048, 256, 0, stream>>>(A, Gt, lvp, rvp, num, den);
    out_kernel<<<1024, 256, 0, stream>>>(num, den, out);
}

// Round 6
// 143.534 us; speedup vs baseline: 1.8990x; 1.8990x over previous
//
#include <hip/hip_runtime.h>
#include <hip/hip_bf16.h>

typedef __attribute__((ext_vector_type(8))) short short8;
typedef __attribute__((ext_vector_type(4))) float floatx4;

#define NN 4096

static __device__ __forceinline__ unsigned f2bf_rne(float x) {
    union { float f; unsigned u; } v; v.f = x;
    unsigned r = v.u + 0x7fffu + ((v.u >> 16) & 1u);
    return r >> 16;
}
static __device__ __forceinline__ float bf2f(unsigned hi) {
    union { unsigned u; float f; } v; v.u = hi << 16; return v.f;
}

// ---- prep (fused wc): per-block computes Wc=W1@W2, w1·alpha; then
// G = X@Wc (bf16 hi/lo MFMA) -> Gt bf16 [b*64+c][4096]; lv/rv fp32.
__global__ __launch_bounds__(256, 4)
void prep_kernel(const float* __restrict__ X,
                 const float* __restrict__ W1,
                 const float* __restrict__ W2,
                 const float* __restrict__ alpha,
                 unsigned short* __restrict__ Gt,
                 float* __restrict__ lv,
                 float* __restrict__ rv) {
    __shared__ __align__(16) char sm[53248];
    float* W1s  = (float*)sm;                 // [64][68]
    float* W2s  = (float*)(sm + 17408);       // [64][68]
    float* Wcst = (float*)(sm + 34816);       // Wc^T: [n][k] stride 68
    float* w1s  = (float*)(sm + 52224);       // [128]
    float* als  = (float*)(sm + 52736);       // [128]
    float* GsT  = (float*)sm;                 // epilogue reuse: [64][68]

    const int t = threadIdx.x;
    const int row0 = blockIdx.x * 64;         // flat b*N + n
    const int b = row0 >> 12, n0 = row0 & (NN - 1);
    const int w = t >> 6, lane = t & 63;
    const int m = lane & 15, q = lane >> 4;

    // issue X loads early (consumed much later)
    const int row = row0 + w * 16 + m;
    const float* xp = X + (size_t)row * 64;
    float4 x0 = *(const float4*)(xp + q * 8);
    float4 x1 = *(const float4*)(xp + q * 8 + 4);
    float4 x2 = *(const float4*)(xp + 32 + q * 8);
    float4 x3 = *(const float4*)(xp + 32 + q * 8 + 4);

    #pragma unroll
    for (int s = 0; s < 4; ++s) {
        int idx = s * 1024 + t * 4;
        int r = idx >> 6, cc = idx & 63;
        *(float4*)&W1s[r * 68 + cc] = *(const float4*)(W1 + idx);
        *(float4*)&W2s[r * 68 + cc] = *(const float4*)(W2 + idx);
    }
    if (t < 128) als[t] = alpha[t];
    __syncthreads();

    // Wc^T: thread (k = t>>2, nq = t&3) computes Wc[k][n], n in [nq*16, nq*16+16)
    {
        const int k = t >> 2, nq = t & 3;
        float acc[16];
        #pragma unroll
        for (int i = 0; i < 16; ++i) acc[i] = 0.f;
        for (int mm = 0; mm < 64; ++mm) {
            float w1v = W1s[k * 68 + mm];
            #pragma unroll
            for (int i = 0; i < 16; ++i)
                acc[i] += w1v * W2s[mm * 68 + nq * 16 + i];
        }
        #pragma unroll
        for (int i = 0; i < 16; ++i)
            Wcst[(nq * 16 + i) * 68 + k] = acc[i];
    }
    if (t < 64) {   // w1a = {W1@aL, W1@aR}
        float sl = 0.f, sr = 0.f;
        for (int cc2 = 0; cc2 < 64; ++cc2) {
            float wv = W1s[t * 68 + cc2];
            sl += wv * als[cc2];
            sr += wv * als[64 + cc2];
        }
        w1s[t] = sl; w1s[64 + t] = sr;
    }
    __syncthreads();

    const float xs[16] = {x0.x,x0.y,x0.z,x0.w, x1.x,x1.y,x1.z,x1.w,
                          x2.x,x2.y,x2.z,x2.w, x3.x,x3.y,x3.z,x3.w};

    // lv/rv fp32 (R4-proven)
    float pl = 0.f, pr = 0.f;
    #pragma unroll
    for (int ks = 0; ks < 2; ++ks)
        #pragma unroll
        for (int j = 0; j < 8; ++j) {
            int k = ks * 32 + q * 8 + j;
            float xv = xs[ks * 8 + j];
            pl += xv * w1s[k];
            pr += xv * w1s[64 + k];
        }
    pl += __shfl_xor(pl, 16, 64); pl += __shfl_xor(pl, 32, 64);
    pr += __shfl_xor(pr, 16, 64); pr += __shfl_xor(pr, 32, 64);
    if (q == 0) { lv[row] = pl; rv[row] = pr; }

    // bf16 hi/lo A-fragments
    short8 ah[2], al[2];
    #pragma unroll
    for (int ks = 0; ks < 2; ++ks)
        #pragma unroll
        for (int j = 0; j < 8; ++j) {
            float f = xs[ks * 8 + j];
            unsigned hb = f2bf_rne(f);
            float res = f - bf2f(hb);
            ah[ks][j] = (short)hb;
            al[ks][j] = (short)f2bf_rne(res);
        }

    // B-frags from Wcst
    short8 bfr[4][2];
    #pragma unroll
    for (int nt = 0; nt < 4; ++nt)
        #pragma unroll
        for (int ks = 0; ks < 2; ++ks) {
            const float* wp = &Wcst[(nt * 16 + m) * 68 + ks * 32 + q * 8];
            float4 w0 = *(const float4*)wp;
            float4 w1 = *(const float4*)(wp + 4);
            short8 bf;
            bf[0] = (short)f2bf_rne(w0.x); bf[1] = (short)f2bf_rne(w0.y);
            bf[2] = (short)f2bf_rne(w0.z); bf[3] = (short)f2bf_rne(w0.w);
            bf[4] = (short)f2bf_rne(w1.x); bf[5] = (short)f2bf_rne(w1.y);
            bf[6] = (short)f2bf_rne(w1.z); bf[7] = (short)f2bf_rne(w1.w);
            bfr[nt][ks] = bf;
        }

    floatx4 acc[4] = {{0,0,0,0},{0,0,0,0},{0,0,0,0},{0,0,0,0}};
    #pragma unroll
    for (int ks = 0; ks < 2; ++ks)
        #pragma unroll
        for (int nt = 0; nt < 4; ++nt) {
            acc[nt] = __builtin_amdgcn_mfma_f32_16x16x32_bf16(ah[ks], bfr[nt][ks], acc[nt], 0, 0, 0);
            acc[nt] = __builtin_amdgcn_mfma_f32_16x16x32_bf16(al[ks], bfr[nt][ks], acc[nt], 0, 0, 0);
        }

    __syncthreads();    // all Wcst/W1s reads done; sm@0 reused as GsT
    #pragma unroll
    for (int nt = 0; nt < 4; ++nt)
        #pragma unroll
        for (int rg = 0; rg < 4; ++rg)
            GsT[(nt * 16 + m) * 68 + w * 16 + q * 4 + rg] = acc[nt][rg];
    __syncthreads();
    unsigned* Gu = (unsigned*)Gt;
    #pragma unroll
    for (int it2 = 0; it2 < 8; ++it2) {
        int c2 = (t >> 5) + it2 * 8;
        int np = t & 31;
        unsigned lo = f2bf_rne(GsT[c2 * 68 + 2 * np]);
        unsigned hi = f2bf_rne(GsT[c2 * 68 + 2 * np + 1]);
        Gu[(((((size_t)(b * 64 + c2)) << 12) + n0) >> 1) + np] = lo | (hi << 16);
    }
}

// ---- attn: block = (i-tile 64, b), 1024 thr = 4 groups x 4 waves; group g owns
// j in [g*1024,(g+1)*1024). Producer-computes-E into LDS A-frag layout; named-reg
// depth-2 prefetch (NO dynamically-indexed arrays); ones-MFMA den; fused divide
// + direct out store (no atomics / workspace zero / out kernel).
__global__ __launch_bounds__(1024, 4)
void attn_kernel(const float* __restrict__ A,
                 const unsigned short* __restrict__ Gt,
                 const float* __restrict__ lv,
                 const float* __restrict__ rv,
                 float* __restrict__ out) {
    __shared__ __align__(16) char sm[57600];
    float* rs = (float*)sm;                              // [4096]
    float* lis = (float*)(sm + 16384);                   // [64]
    unsigned short* Es = (unsigned short*)(sm + 16640);  // [4][64*40]
    unsigned short* Gs = (unsigned short*)(sm + 37120);  // [4][64*40]

    const int bx = blockIdx.x;
    const int i0 = (bx & 63) * 64;
    const int b  = bx >> 6;
    const int t = threadIdx.x;
    const int wave = t >> 6, lane = t & 63;
    const int grp = wave >> 2, wsub = wave & 3;
    const int m = lane & 15, q = lane >> 4;
    const int irow = wsub * 16 + (lane >> 2);
    const int jseg = lane & 3;

    *(float4*)&rs[t * 4] = *(const float4*)(rv + b * NN + t * 4);
    if (t < 64) lis[t] = lv[b * NN + i0 + t] * 1.44269504f;   // fold log2e

    const float* aRow = A + (size_t)(i0 + irow) * NN + grp * 1024 + jseg * 8;
    const unsigned short* gRow = Gt + (((size_t)(b * 64 + irow)) << 12) + grp * 1024 + jseg * 8;
    const int jd = (i0 + irow) - grp * 1024;                  // diag col in group range
    const bool diag_grp = (((i0 + irow) >> 10) == grp);

    unsigned short* EsG = Es + grp * 2560;
    unsigned short* GsG = Gs + grp * 2560;

    // prefetch chunks 0 (A-regs) and 1 (B-regs)
    float4 a0A = *(const float4*)(aRow);
    float4 a1A = *(const float4*)(aRow + 4);
    uint4  gA  = *(const uint4*)(gRow);
    float4 a0B = *(const float4*)(aRow + 32);
    float4 a1B = *(const float4*)(aRow + 36);
    uint4  gB  = *(const uint4*)(gRow + 32);

    __syncthreads();
    const float li = lis[irow];

    floatx4 acc0 = {0,0,0,0}, acc1 = {0,0,0,0}, acc2 = {0,0,0,0},
            acc3 = {0,0,0,0}, accd = {0,0,0,0};
    short8 ones;
    #pragma unroll
    for (int e = 0; e < 8; ++e) ones[e] = (short)0x3F80;      // bf16 1.0

    auto genE = [&](float4 a0, float4 a1, int chunk) -> uint4 {
        const int jl = chunk * 32 + jseg * 8;
        float aa[8] = {a0.x, a0.y, a0.z, a0.w, a1.x, a1.y, a1.z, a1.w};
        if (diag_grp && (jd >> 5) == chunk) {
            const int dd = jd - jl;
            #pragma unroll
            for (int e = 0; e < 8; ++e) if (dd == e) aa[e] = 1.0f;
        }
        const float4 r0 = *(const float4*)&rs[grp * 1024 + jl];
        const float4 r1 = *(const float4*)&rs[grp * 1024 + jl + 4];
        const float rr[8] = {r0.x, r0.y, r0.z, r0.w, r1.x, r1.y, r1.z, r1.w};
        unsigned ew[4];
        #pragma unroll
        for (int e2 = 0; e2 < 4; ++e2) {
            float s0 = li * rr[2 * e2], s1 = li * rr[2 * e2 + 1];
            s0 = fmaxf(s0, 0.01f * s0);                       // leaky_relu
            s1 = fmaxf(s1, 0.01f * s1);
            float e0 = exp2f(s0) * aa[2 * e2];
            float e1 = exp2f(s1) * aa[2 * e2 + 1];
            ew[e2] = __builtin_amdgcn_perm(__float_as_uint(e1) + 0x8000u,
                                           __float_as_uint(e0) + 0x8000u, 0x07060302u);
        }
        return uint4{ew[0], ew[1], ew[2], ew[3]};
    };

    const int eoff = irow * 40 + jseg * 8;
    for (int c = 0; c < 32; c += 2) {
        // ---- even half: chunk c (A-regs) ----
        uint4 eA = genE(a0A, a1A, c);
        uint4 gsvA = gA;
        { int jn = (c + 2 < 32) ? (c + 2) * 32 : c * 32;      // clamp tail
          a0A = *(const float4*)(aRow + jn);
          a1A = *(const float4*)(aRow + jn + 4);
          gA  = *(const uint4*)(gRow + jn); }
        __syncthreads();                                      // prior MFMA reads done
        *(uint4*)&EsG[eoff] = eA;
        *(uint4*)&GsG[eoff] = gsvA;
        __syncthreads();                                      // tiles ready
        {
            short8 afr = *(const short8*)&EsG[(wsub * 16 + m) * 40 + q * 8];
            short8 b0  = *(const short8*)&GsG[(m)      * 40 + q * 8];
            short8 b1  = *(const short8*)&GsG[(16 + m) * 40 + q * 8];
            short8 b2  = *(const short8*)&GsG[(32 + m) * 40 + q * 8];
            short8 b3  = *(const short8*)&GsG[(48 + m) * 40 + q * 8];
            acc0 = __builtin_amdgcn_mfma_f32_16x16x32_bf16(afr, b0, acc0, 0, 0, 0);
            acc1 = __builtin_amdgcn_mfma_f32_16x16x32_bf16(afr, b1, acc1, 0, 0, 0);
            acc2 = __builtin_amdgcn_mfma_f32_16x16x32_bf16(afr, b2, acc2, 0, 0, 0);
            acc3 = __builtin_amdgcn_mfma_f32_16x16x32_bf16(afr, b3, acc3, 0, 0, 0);
            accd = __builtin_amdgcn_mfma_f32_16x16x32_bf16(afr, ones, accd, 0, 0, 0);
        }
        // ---- odd half: chunk c+1 (B-regs) ----
        uint4 eB = genE(a0B, a1B, c + 1);
        uint4 gsvB = gB;
        { int jn = (c + 3 < 32) ? (c + 3) * 32 : (c + 1) * 32;
          a0B = *(const float4*)(aRow + jn);
          a1B = *(const float4*)(aRow + jn + 4);
          gB  = *(const uint4*)(gRow + jn); }
        __syncthreads();
        *(uint4*)&EsG[eoff] = eB;
        *(uint4*)&GsG[eoff] = gsvB;
        __syncthreads();
        {
            short8 afr = *(const short8*)&EsG[(wsub * 16 + m) * 40 + q * 8];
            short8 b0  = *(const short8*)&GsG[(m)      * 40 + q * 8];
            short8 b1  = *(const short8*)&GsG[(16 + m) * 40 + q * 8];
            short8 b2  = *(const short8*)&GsG[(32 + m) * 40 + q * 8];
            short8 b3  = *(const short8*)&GsG[(48 + m) * 40 + q * 8];
            acc0 = __builtin_amdgcn_mfma_f32_16x16x32_bf16(afr, b0, acc0, 0, 0, 0);
            acc1 = __builtin_amdgcn_mfma_f32_16x16x32_bf16(afr, b1, acc1, 0, 0, 0);
            acc2 = __builtin_amdgcn_mfma_f32_16x16x32_bf16(afr, b2, acc2, 0, 0, 0);
            acc3 = __builtin_amdgcn_mfma_f32_16x16x32_bf16(afr, b3, acc3, 0, 0, 0);
            accd = __builtin_amdgcn_mfma_f32_16x16x32_bf16(afr, ones, accd, 0, 0, 0);
        }
    }

    // ---- epilogue: two-pass cross-group reduction in LDS, divide, store out ----
    __syncthreads();
    float* red = (float*)sm;                 // [2][64][68]; col 64 holds den
    const int il = t >> 4, c4 = t & 15;
    float4 osum = {0.f, 0.f, 0.f, 0.f};
    float dsum = 0.f;
    #pragma unroll
    for (int pass = 0; pass < 2; ++pass) {
        if ((grp >> 1) == pass) {
            float* rp_ = red + (grp & 1) * 4352;
            #pragma unroll
            for (int nt = 0; nt < 4; ++nt) {
                floatx4 av = nt == 0 ? acc0 : nt == 1 ? acc1 : nt == 2 ? acc2 : acc3;
                #pragma unroll
                for (int rg = 0; rg < 4; ++rg)
                    rp_[(wsub * 16 + q * 4 + rg) * 68 + nt * 16 + m] = av[rg];
            }
            if (m == 0) {
                #pragma unroll
                for (int rg = 0; rg < 4; ++rg)
                    rp_[(wsub * 16 + q * 4 + rg) * 68 + 64] = accd[rg];
            }
        }
        __syncthreads();
        {
            float4 v0 = *(const float4*)&red[il * 68 + c4 * 4];
            float4 v1 = *(const float4*)&red[4352 + il * 68 + c4 * 4];
            osum.x += v0.x + v1.x; osum.y += v0.y + v1.y;
            osum.z += v0.z + v1.z; osum.w += v0.w + v1.w;
            dsum += red[il * 68 + 64] + red[4352 + il * 68 + 64];
        }
        __syncthreads();
    }
    const float rinv = 1.0f / dsum;
    float4 o;
    o.x = osum.x * rinv; o.y = osum.y * rinv;
    o.z = osum.z * rinv; o.w = osum.w * rinv;
    *(float4*)(out + (((size_t)(b * NN + i0 + il)) << 6) + c4 * 4) = o;
}

extern "C" void kernel_launch(void* const* d_in, const int* in_sizes, int n_in,
                              void* d_out, int out_size, void* d_ws, size_t ws_size,
                              hipStream_t stream) {
    const float* X     = (const float*)d_in[0];
    const float* A     = (const float*)d_in[1];
    const float* W1    = (const float*)d_in[2];
    const float* W2    = (const float*)d_in[3];
    const float* alpha = (const float*)d_in[4];
    float* out = (float*)d_out;

    char* ws = (char*)d_ws;
    unsigned short* Gt = (unsigned short*)(ws);            // 2 MiB
    float* lvp = (float*)(ws + 2097152);                   // 64 KiB
    float* rvp = (float*)(ws + 2097152 + 65536);           // 64 KiB

    prep_kernel<<<256, 256, 0, stream>>>(X, W1, W2, alpha, Gt, lvp, rvp);
    attn_kernel<<<256, 1024, 0, stream>>>(A, Gt, lvp, rvp, out);
}